// Round 6
// baseline (597.509 us; speedup 1.0000x reference)
//
#include <hip/hip_runtime.h>
#include <cstddef>
#include <cstdint>

#define NN 50000
#define NE 600000
#define SCAN_BLOCKS ((NN + 1023) / 1024)   // 49
#define PH ((size_t)NN * 32)               // elements per channel-phase

typedef __attribute__((ext_vector_type(8))) short bf16x8;
typedef __attribute__((ext_vector_type(4))) float f32x4;

#define SWZ(x) (((x) ^ ((x) >> 2)) & 3)

__device__ __forceinline__ float bf2f(ushort u) {
    return __uint_as_float(((uint32_t)u) << 16);
}
__device__ __forceinline__ ushort f2bf(float f) {   // round-to-nearest-even
    uint32_t b = __float_as_uint(f);
    return (ushort)((b + 0x7FFF + ((b >> 16) & 1)) >> 16);
}

// ---------------------------------------------------------------- weights->bf16 transposed
// Wt[c][k] layouts: wf1[128][32] wf2[128][32] wg[l][128][128] wfg[l][128][256] wl1[128][256]
__global__ __launch_bounds__(256)
void convert_weights(const float* __restrict__ f1W, const float* __restrict__ f2W,
                     const float* __restrict__ gW, const float* __restrict__ fgW,
                     const float* __restrict__ l1W, ushort* __restrict__ wt)
{
    int i = blockIdx.x * 256 + threadIdx.x;          // 0 .. 335871
    if (i >= 335872) return;
    float v;
    if (i < 4096) {                                  // wf1
        int c = i >> 5, k = i & 31;
        v = f1W[k * 128 + c];
    } else if (i < 8192) {                           // wf2
        int j = i - 4096; int c = j >> 5, k = j & 31;
        v = f2W[k * 128 + c];
    } else if (i < 8192 + 98304) {                   // wg
        int j = i - 8192; int l = j >> 14, r = j & 16383;
        int c = r >> 7, k = r & 127;
        v = gW[l * 16384 + k * 128 + c];
    } else if (i < 8192 + 98304 + 196608) {          // wfg
        int j = i - (8192 + 98304); int l = j >> 15, r = j & 32767;
        int c = r >> 8, k = r & 255;
        v = fgW[l * 32768 + k * 128 + c];
    } else {                                         // wl1
        int j = i - (8192 + 98304 + 196608);
        int c = j >> 8, k = j & 255;
        v = l1W[k * 128 + c];
    }
    wt[i] = f2bf(v);
}

// ---------------------------------------------------------------- preproc (out bf16)
__global__ __launch_bounds__(256)
void preproc_kernel(const float* __restrict__ x, const float* __restrict__ W,
                    const float* __restrict__ b, ushort* __restrict__ out)
{
    __shared__ float Wl[512];
    __shared__ float bl[32];
    int tx = threadIdx.x;
    Wl[tx]       = W[tx];
    Wl[tx + 256] = W[tx + 256];
    if (tx < 32) bl[tx] = b[tx];
    __syncthreads();
    int n = blockIdx.x * 256 + tx;
    if (n >= NN) return;
    float xr[16];
    const float4* xp = (const float4*)(x + (size_t)n * 16);
#pragma unroll
    for (int q = 0; q < 4; ++q) {
        float4 v = xp[q];
        xr[q*4+0]=v.x; xr[q*4+1]=v.y; xr[q*4+2]=v.z; xr[q*4+3]=v.w;
    }
    float acc[32];
#pragma unroll
    for (int c = 0; c < 32; ++c) acc[c] = bl[c];
#pragma unroll
    for (int k = 0; k < 16; ++k)
#pragma unroll
        for (int c = 0; c < 32; ++c)
            acc[c] = fmaf(xr[k], Wl[k*32+c], acc[c]);
    ushort4* op = (ushort4*)(out + (size_t)n * 32);
#pragma unroll
    for (int q = 0; q < 8; ++q) {
        ushort4 v;
        v.x = f2bf(fmaxf(acc[q*4+0], 0.f));
        v.y = f2bf(fmaxf(acc[q*4+1], 0.f));
        v.z = f2bf(fmaxf(acc[q*4+2], 0.f));
        v.w = f2bf(fmaxf(acc[q*4+3], 0.f));
        op[q] = v;
    }
}

// ---------------------------------------------------------------- plain MFMA GEMM (fc_in1)
__global__ __launch_bounds__(128)
void gemm_mfma(const ushort* __restrict__ A1, int K1,
               const ushort* __restrict__ Wt, const float* __restrict__ bias,
               ushort* __restrict__ out, int nrows)
{
    __shared__ ushort Atile[64 * 32];
    __shared__ ushort Btile[128 * 32];
    const int tx   = threadIdx.x;
    const int wave = tx >> 6;
    const int lane = tx & 63;
    const int bm   = blockIdx.x * 64;
    const int Ktot = K1;

    const int rs  = lane >> 2;
    const int chn = (lane & 3) ^ SWZ(rs);
    const int m    = lane & 15;
    const int quad = lane >> 4;
    const int slot = quad ^ SWZ(m);

    f32x4 acc0[8], acc1[8];
#pragma unroll
    for (int t = 0; t < 8; ++t) {
        acc0[t] = (f32x4){0.f, 0.f, 0.f, 0.f};
        acc1[t] = (f32x4){0.f, 0.f, 0.f, 0.f};
    }

    for (int kk = 0; kk < Ktot; kk += 32) {
#pragma unroll
        for (int i = 0; i < 2; ++i) {
            int seg = wave + 2 * i;
            int row = seg * 16 + rs;
            int ar  = bm + row; if (ar >= nrows) ar = nrows - 1;
            __builtin_amdgcn_global_load_lds(
                (const __attribute__((address_space(1))) void*)
                    (A1 + (size_t)ar * K1 + kk + chn * 8),
                (__attribute__((address_space(3))) void*)(Atile + seg * 512),
                16, 0, 0);
        }
#pragma unroll
        for (int i = 0; i < 4; ++i) {
            int seg = wave + 2 * i;
            int col = seg * 16 + rs;
            __builtin_amdgcn_global_load_lds(
                (const __attribute__((address_space(1))) void*)
                    (Wt + (size_t)col * Ktot + kk + chn * 8),
                (__attribute__((address_space(3))) void*)(Btile + seg * 512),
                16, 0, 0);
        }
        __syncthreads();
        bf16x8 af0 = *(const bf16x8*)(Atile + (wave * 32 + m) * 32 + slot * 8);
        bf16x8 af1 = *(const bf16x8*)(Atile + (wave * 32 + 16 + m) * 32 + slot * 8);
#pragma unroll
        for (int t = 0; t < 8; ++t) {
            bf16x8 bfr = *(const bf16x8*)(Btile + (t * 16 + m) * 32 + slot * 8);
            acc0[t] = __builtin_amdgcn_mfma_f32_16x16x32_bf16(af0, bfr, acc0[t], 0, 0, 0);
            acc1[t] = __builtin_amdgcn_mfma_f32_16x16x32_bf16(af1, bfr, acc1[t], 0, 0, 0);
        }
        __syncthreads();
    }

#pragma unroll
    for (int half = 0; half < 2; ++half) {
        const int orow0 = bm + wave * 32 + half * 16 + quad * 4;
#pragma unroll
        for (int t = 0; t < 8; ++t) {
            int col = t * 16 + m;
            float bb = bias[col];
            f32x4 a = half ? acc1[t] : acc0[t];
#pragma unroll
            for (int r = 0; r < 4; ++r) {
                int row = orow0 + r;
                if (row < nrows)
                    out[(size_t)row * 128 + col] = f2bf(fmaxf(a[r] + bb, 0.f));
            }
        }
    }
}

// ---------------------------------------------------------------- fused GEMM
// X = relu([A1|A2] @ Wt^T + bias); out_hw = X @ Wg^T
// A1 row-major [n][K1]; A2 phase-major [4][N][32]; out_hw phase-major.
__global__ __launch_bounds__(128)
void gemm_fused(const ushort* __restrict__ A1, int K1,
                const ushort* __restrict__ A2, int K2,
                const ushort* __restrict__ Wt, const float* __restrict__ bias,
                const ushort* __restrict__ Wg,
                ushort* __restrict__ out_hw, int nrows)
{
    __shared__ ushort Atile[64 * 32];
    __shared__ ushort Btile[128 * 32];
    __shared__ ushort Xt[64 * 128];
    const int tx   = threadIdx.x;
    const int wave = tx >> 6;
    const int lane = tx & 63;
    const int bm   = blockIdx.x * 64;
    const int Ktot = K1 + K2;

    const int rs  = lane >> 2;
    const int chn = (lane & 3) ^ SWZ(rs);
    const int m    = lane & 15;
    const int quad = lane >> 4;
    const int slot = quad ^ SWZ(m);

    f32x4 acc0[8], acc1[8];
#pragma unroll
    for (int t = 0; t < 8; ++t) {
        acc0[t] = (f32x4){0.f, 0.f, 0.f, 0.f};
        acc1[t] = (f32x4){0.f, 0.f, 0.f, 0.f};
    }

    // ---- stage 1 ----
    for (int kk = 0; kk < Ktot; kk += 32) {
#pragma unroll
        for (int i = 0; i < 2; ++i) {
            int seg = wave + 2 * i;
            int row = seg * 16 + rs;
            int ar  = bm + row; if (ar >= nrows) ar = nrows - 1;
            const ushort* ap;
            if (kk < K1) ap = A1 + (size_t)ar * K1 + kk + chn * 8;
            else         ap = A2 + (size_t)((kk - K1) >> 5) * PH + (size_t)ar * 32 + chn * 8;
            __builtin_amdgcn_global_load_lds(
                (const __attribute__((address_space(1))) void*)ap,
                (__attribute__((address_space(3))) void*)(Atile + seg * 512),
                16, 0, 0);
        }
#pragma unroll
        for (int i = 0; i < 4; ++i) {
            int seg = wave + 2 * i;
            int col = seg * 16 + rs;
            __builtin_amdgcn_global_load_lds(
                (const __attribute__((address_space(1))) void*)
                    (Wt + (size_t)col * Ktot + kk + chn * 8),
                (__attribute__((address_space(3))) void*)(Btile + seg * 512),
                16, 0, 0);
        }
        __syncthreads();
        bf16x8 af0 = *(const bf16x8*)(Atile + (wave * 32 + m) * 32 + slot * 8);
        bf16x8 af1 = *(const bf16x8*)(Atile + (wave * 32 + 16 + m) * 32 + slot * 8);
#pragma unroll
        for (int t = 0; t < 8; ++t) {
            bf16x8 bfr = *(const bf16x8*)(Btile + (t * 16 + m) * 32 + slot * 8);
            acc0[t] = __builtin_amdgcn_mfma_f32_16x16x32_bf16(af0, bfr, acc0[t], 0, 0, 0);
            acc1[t] = __builtin_amdgcn_mfma_f32_16x16x32_bf16(af1, bfr, acc1[t], 0, 0, 0);
        }
        __syncthreads();
    }

    // ---- epilogue 1: bias+relu -> Xt (swizzled A-layout), zero acc ----
#pragma unroll
    for (int half = 0; half < 2; ++half) {
        int rbase = wave * 32 + half * 16 + quad * 4;
#pragma unroll
        for (int t = 0; t < 8; ++t) {
            int col = t * 16 + m;
            float bb = bias[col];
            int c32 = col >> 5, within = col & 7, ks = (col >> 3) & 3;
            f32x4 a = half ? acc1[t] : acc0[t];
#pragma unroll
            for (int r = 0; r < 4; ++r) {
                int row = rbase + r;
                int pos = ks ^ SWZ(row & 15);
                Xt[row * 128 + c32 * 32 + pos * 8 + within] =
                    f2bf(fmaxf(a[r] + bb, 0.f));
            }
        }
    }
#pragma unroll
    for (int t = 0; t < 8; ++t) {
        acc0[t] = (f32x4){0.f, 0.f, 0.f, 0.f};
        acc1[t] = (f32x4){0.f, 0.f, 0.f, 0.f};
    }
    __syncthreads();

    // ---- stage 2: out_hw = X @ Wg^T (K=128) ----
    for (int c32 = 0; c32 < 4; ++c32) {
        int kk = c32 * 32;
#pragma unroll
        for (int i = 0; i < 4; ++i) {
            int seg = wave + 2 * i;
            int col = seg * 16 + rs;
            __builtin_amdgcn_global_load_lds(
                (const __attribute__((address_space(1))) void*)
                    (Wg + (size_t)col * 128 + kk + chn * 8),
                (__attribute__((address_space(3))) void*)(Btile + seg * 512),
                16, 0, 0);
        }
        __syncthreads();
        bf16x8 af0 = *(const bf16x8*)(Xt + (wave * 32 + m) * 128 + kk + slot * 8);
        bf16x8 af1 = *(const bf16x8*)(Xt + (wave * 32 + 16 + m) * 128 + kk + slot * 8);
#pragma unroll
        for (int t = 0; t < 8; ++t) {
            bf16x8 bfr = *(const bf16x8*)(Btile + (t * 16 + m) * 32 + slot * 8);
            acc0[t] = __builtin_amdgcn_mfma_f32_16x16x32_bf16(af0, bfr, acc0[t], 0, 0, 0);
            acc1[t] = __builtin_amdgcn_mfma_f32_16x16x32_bf16(af1, bfr, acc1[t], 0, 0, 0);
        }
        __syncthreads();
    }

    // ---- epilogue 2: phase-major store ----
#pragma unroll
    for (int half = 0; half < 2; ++half) {
        const int orow0 = bm + wave * 32 + half * 16 + quad * 4;
#pragma unroll
        for (int t = 0; t < 8; ++t) {
            int col = t * 16 + m;
            ushort* obase = out_hw + (size_t)(col >> 5) * PH + (col & 31);
            f32x4 a = half ? acc1[t] : acc0[t];
#pragma unroll
            for (int r = 0; r < 4; ++r) {
                int row = orow0 + r;
                if (row < nrows)
                    obase[(size_t)row * 32] = f2bf(a[r]);
            }
        }
    }
}

// ---------------------------------------------------------------- last fused
// X = relu(nid@Wfg5_t + agg@Wfg5_b + b5); HH = relu(nid@l1t + X@l1b + l1bias);
// out = sigmoid(HH @ l2W + l2b).  agg is phase-major.
__global__ __launch_bounds__(128)
void gemm_last(const ushort* __restrict__ nid, const ushort* __restrict__ agg,
               const ushort* __restrict__ Wt, const float* __restrict__ bias5,
               const ushort* __restrict__ Wl1, const float* __restrict__ l1b,
               const float* __restrict__ l2W, const float* __restrict__ l2b,
               float* __restrict__ out, int nrows)
{
    __shared__ ushort Atile[64 * 32];
    __shared__ ushort Btile[128 * 32];
    __shared__ ushort Xt[64 * 128];
    __shared__ float  w2s[256];
    const int tx   = threadIdx.x;
    const int wave = tx >> 6;
    const int lane = tx & 63;
    const int bm   = blockIdx.x * 64;

    w2s[tx]       = l2W[tx];
    w2s[tx + 128] = l2W[tx + 128];

    const int rs  = lane >> 2;
    const int chn = (lane & 3) ^ SWZ(rs);
    const int m    = lane & 15;
    const int quad = lane >> 4;
    const int slot = quad ^ SWZ(m);

    f32x4 acc0[8], acc1[8];
#pragma unroll
    for (int t = 0; t < 8; ++t) {
        acc0[t] = (f32x4){0.f, 0.f, 0.f, 0.f};
        acc1[t] = (f32x4){0.f, 0.f, 0.f, 0.f};
    }

    // ---- stage 1: X = relu(nid@t + agg@b + b5), Ktot=256 ----
    for (int kk = 0; kk < 256; kk += 32) {
#pragma unroll
        for (int i = 0; i < 2; ++i) {
            int seg = wave + 2 * i;
            int row = seg * 16 + rs;
            int ar  = bm + row; if (ar >= nrows) ar = nrows - 1;
            const ushort* ap;
            if (kk < 128) ap = nid + (size_t)ar * 128 + kk + chn * 8;
            else          ap = agg + (size_t)((kk - 128) >> 5) * PH + (size_t)ar * 32 + chn * 8;
            __builtin_amdgcn_global_load_lds(
                (const __attribute__((address_space(1))) void*)ap,
                (__attribute__((address_space(3))) void*)(Atile + seg * 512),
                16, 0, 0);
        }
#pragma unroll
        for (int i = 0; i < 4; ++i) {
            int seg = wave + 2 * i;
            int col = seg * 16 + rs;
            __builtin_amdgcn_global_load_lds(
                (const __attribute__((address_space(1))) void*)
                    (Wt + (size_t)col * 256 + kk + chn * 8),
                (__attribute__((address_space(3))) void*)(Btile + seg * 512),
                16, 0, 0);
        }
        __syncthreads();
        bf16x8 af0 = *(const bf16x8*)(Atile + (wave * 32 + m) * 32 + slot * 8);
        bf16x8 af1 = *(const bf16x8*)(Atile + (wave * 32 + 16 + m) * 32 + slot * 8);
#pragma unroll
        for (int t = 0; t < 8; ++t) {
            bf16x8 bfr = *(const bf16x8*)(Btile + (t * 16 + m) * 32 + slot * 8);
            acc0[t] = __builtin_amdgcn_mfma_f32_16x16x32_bf16(af0, bfr, acc0[t], 0, 0, 0);
            acc1[t] = __builtin_amdgcn_mfma_f32_16x16x32_bf16(af1, bfr, acc1[t], 0, 0, 0);
        }
        __syncthreads();
    }

    // ---- epilogue 1 -> Xt ----
#pragma unroll
    for (int half = 0; half < 2; ++half) {
        int rbase = wave * 32 + half * 16 + quad * 4;
#pragma unroll
        for (int t = 0; t < 8; ++t) {
            int col = t * 16 + m;
            float bb = bias5[col];
            int c32 = col >> 5, within = col & 7, ks = (col >> 3) & 3;
            f32x4 a = half ? acc1[t] : acc0[t];
#pragma unroll
            for (int r = 0; r < 4; ++r) {
                int row = rbase + r;
                int pos = ks ^ SWZ(row & 15);
                Xt[row * 128 + c32 * 32 + pos * 8 + within] =
                    f2bf(fmaxf(a[r] + bb, 0.f));
            }
        }
    }
#pragma unroll
    for (int t = 0; t < 8; ++t) {
        acc0[t] = (f32x4){0.f, 0.f, 0.f, 0.f};
        acc1[t] = (f32x4){0.f, 0.f, 0.f, 0.f};
    }
    __syncthreads();

    // ---- stage 2: HH = nid@l1t + X@l1b, Ktot=256 ----
    for (int c8 = 0; c8 < 8; ++c8) {
        int kk = c8 * 32;
        if (c8 < 4) {
#pragma unroll
            for (int i = 0; i < 2; ++i) {
                int seg = wave + 2 * i;
                int row = seg * 16 + rs;
                int ar  = bm + row; if (ar >= nrows) ar = nrows - 1;
                __builtin_amdgcn_global_load_lds(
                    (const __attribute__((address_space(1))) void*)
                        (nid + (size_t)ar * 128 + kk + chn * 8),
                    (__attribute__((address_space(3))) void*)(Atile + seg * 512),
                    16, 0, 0);
            }
        }
#pragma unroll
        for (int i = 0; i < 4; ++i) {
            int seg = wave + 2 * i;
            int col = seg * 16 + rs;
            __builtin_amdgcn_global_load_lds(
                (const __attribute__((address_space(1))) void*)
                    (Wl1 + (size_t)col * 256 + kk + chn * 8),
                (__attribute__((address_space(3))) void*)(Btile + seg * 512),
                16, 0, 0);
        }
        __syncthreads();
        bf16x8 af0, af1;
        if (c8 < 4) {
            af0 = *(const bf16x8*)(Atile + (wave * 32 + m) * 32 + slot * 8);
            af1 = *(const bf16x8*)(Atile + (wave * 32 + 16 + m) * 32 + slot * 8);
        } else {
            int ko = (c8 - 4) * 32;
            af0 = *(const bf16x8*)(Xt + (wave * 32 + m) * 128 + ko + slot * 8);
            af1 = *(const bf16x8*)(Xt + (wave * 32 + 16 + m) * 128 + ko + slot * 8);
        }
#pragma unroll
        for (int t = 0; t < 8; ++t) {
            bf16x8 bfr = *(const bf16x8*)(Btile + (t * 16 + m) * 32 + slot * 8);
            acc0[t] = __builtin_amdgcn_mfma_f32_16x16x32_bf16(af0, bfr, acc0[t], 0, 0, 0);
            acc1[t] = __builtin_amdgcn_mfma_f32_16x16x32_bf16(af1, bfr, acc1[t], 0, 0, 0);
        }
        __syncthreads();
    }

    // ---- epilogue: relu(HH+l1b) @ l2W, sigmoid, write fp32 out ----
    float bb[8];
#pragma unroll
    for (int t = 0; t < 8; ++t) bb[t] = l1b[t * 16 + m];
    float b20 = l2b[0], b21 = l2b[1];
#pragma unroll
    for (int half = 0; half < 2; ++half) {
#pragma unroll
        for (int r = 0; r < 4; ++r) {
            float p0 = 0.f, p1 = 0.f;
#pragma unroll
            for (int t = 0; t < 8; ++t) {
                int col = t * 16 + m;
                f32x4 a = half ? acc1[t] : acc0[t];
                float v = fmaxf(a[r] + bb[t], 0.f);
                p0 = fmaf(v, w2s[col * 2 + 0], p0);
                p1 = fmaf(v, w2s[col * 2 + 1], p1);
            }
#pragma unroll
            for (int mask = 1; mask < 16; mask <<= 1) {
                p0 += __shfl_xor(p0, mask);
                p1 += __shfl_xor(p1, mask);
            }
            if (m == 0) {
                int row = bm + wave * 32 + half * 16 + quad * 4 + r;
                if (row < nrows) {
                    out[(size_t)row * 2 + 0] = 1.f / (1.f + __expf(-(p0 + b20)));
                    out[(size_t)row * 2 + 1] = 1.f / (1.f + __expf(-(p1 + b21)));
                }
            }
        }
    }
}

// ---------------------------------------------------------------- CSR build
__global__ __launch_bounds__(256)
void hist_kernel(const int* __restrict__ dst, int* __restrict__ deg)
{
    int e = blockIdx.x * 256 + threadIdx.x;
    if (e < NE) atomicAdd(&deg[dst[e]], 1);
}

__global__ __launch_bounds__(1024)
void scan1_kernel(const int* __restrict__ deg, int* __restrict__ off,
                  int* __restrict__ bsum)
{
    __shared__ int buf[1024];
    int tx = threadIdx.x;
    int i = blockIdx.x * 1024 + tx;
    int v = (i < NN) ? deg[i] : 0;
    buf[tx] = v;
    __syncthreads();
    for (int s = 1; s < 1024; s <<= 1) {
        int t = (tx >= s) ? buf[tx - s] : 0;
        __syncthreads();
        buf[tx] += t;
        __syncthreads();
    }
    if (i < NN) off[i] = buf[tx] - v;
    if (tx == 1023) bsum[blockIdx.x] = buf[1023];
}

__global__ __launch_bounds__(64)
void scan2_kernel(int* __restrict__ bsum)
{
    __shared__ int buf[64];
    int tx = threadIdx.x;
    int v = (tx < SCAN_BLOCKS) ? bsum[tx] : 0;
    buf[tx] = v;
    __syncthreads();
    for (int s = 1; s < 64; s <<= 1) {
        int t = (tx >= s) ? buf[tx - s] : 0;
        __syncthreads();
        buf[tx] += t;
        __syncthreads();
    }
    if (tx < SCAN_BLOCKS) bsum[tx] = buf[tx] - v;
}

__global__ __launch_bounds__(1024)
void scan3_kernel(int* __restrict__ off, const int* __restrict__ bsum)
{
    int i = blockIdx.x * 1024 + threadIdx.x;
    if (i < NN) off[i] += bsum[blockIdx.x];
    if (i == 0) off[NN] = NE;
}

__global__ __launch_bounds__(256)
void permute_kernel(const int* __restrict__ src, const int* __restrict__ dst,
                    const float* __restrict__ w, const int* __restrict__ off,
                    int* __restrict__ cursor, unsigned long long* __restrict__ esw)
{
    int e = blockIdx.x * 256 + threadIdx.x;
    if (e >= NE) return;
    int d = dst[e];
    int p = off[d] + atomicAdd(&cursor[d], 1);
    unsigned long long packed = (unsigned int)src[e] |
        ((unsigned long long)(unsigned int)__float_as_uint(w[e]) << 32);
    __builtin_nontemporal_store(packed, &esw[p]);
}

// ---------------------------------------------------------------- gather (one phase)
// hw_ph / agg_ph point at one phase region [N][32] (3.2 MB, L2-resident).
// agg_ph[n][c] = bf16(relu(sum_e w*hw_ph[src][c] + gbias[c])); 4 lanes/node x 8 ch.
__global__ __launch_bounds__(256)
void gather_agg(const ushort* __restrict__ hw_ph, const int2* __restrict__ esw,
                const int* __restrict__ off, const float* __restrict__ gbias,
                ushort* __restrict__ agg_ph)
{
    int t = blockIdx.x * 256 + threadIdx.x;
    int n = t >> 2;
    if (n >= NN) return;
    int lane = t & 3;
    const ushort* hp = hw_ph + lane * 8;
    int e0 = off[n], e1 = off[n + 1];
    float acc[8];
#pragma unroll
    for (int j = 0; j < 8; ++j) acc[j] = 0.f;
    int e = e0;
    for (; e + 1 < e1; e += 2) {
        int2 p0 = esw[e];
        int2 p1 = esw[e + 1];
        float w0 = __int_as_float(p0.y);
        float w1 = __int_as_float(p1.y);
        bf16x8 v0 = *(const bf16x8*)(hp + (size_t)p0.x * 32);
        bf16x8 v1 = *(const bf16x8*)(hp + (size_t)p1.x * 32);
#pragma unroll
        for (int j = 0; j < 8; ++j)
            acc[j] += bf2f((ushort)v0[j]) * w0 + bf2f((ushort)v1[j]) * w1;
    }
    if (e < e1) {
        int2 p0 = esw[e];
        float w0 = __int_as_float(p0.y);
        bf16x8 v0 = *(const bf16x8*)(hp + (size_t)p0.x * 32);
#pragma unroll
        for (int j = 0; j < 8; ++j)
            acc[j] += bf2f((ushort)v0[j]) * w0;
    }
    int c0 = lane * 8;
    bf16x8 o;
#pragma unroll
    for (int j = 0; j < 8; ++j)
        o[j] = (short)f2bf(fmaxf(acc[j] + gbias[c0 + j], 0.f));
    *(bf16x8*)(agg_ph + (size_t)n * 32 + c0) = o;
}

// ---------------------------------------------------------------- launch
extern "C" void kernel_launch(void* const* d_in, const int* in_sizes, int n_in,
                              void* d_out, int out_size, void* d_ws, size_t ws_size,
                              hipStream_t stream)
{
    const float* x    = (const float*)d_in[0];
    const int*   esrc = (const int*)  d_in[1];
    const int*   edst = (const int*)  d_in[2];
    const float* ew   = (const float*)d_in[3];
    const float* preW = (const float*)d_in[4];
    const float* preb = (const float*)d_in[5];
    const float* f1W  = (const float*)d_in[6];
    const float* f1b  = (const float*)d_in[7];
    const float* f2W  = (const float*)d_in[8];
    const float* f2b  = (const float*)d_in[9];
    const float* gW   = (const float*)d_in[10];
    const float* gb   = (const float*)d_in[11];
    const float* fgW  = (const float*)d_in[12];
    const float* fgb  = (const float*)d_in[13];
    const float* l1W  = (const float*)d_in[14];
    const float* l1b  = (const float*)d_in[15];
    const float* l2W  = (const float*)d_in[16];
    const float* l2b  = (const float*)d_in[17];
    float* out = (float*)d_out;

    ushort* wt   = (ushort*)d_ws;
    ushort* wf1  = wt;                          //   4096
    ushort* wf2  = wf1 + 4096;                  //   4096
    ushort* wg   = wf2 + 4096;                  //  98304
    ushort* wfg  = wg  + 98304;                 // 196608
    ushort* wl1  = wfg + 196608;                //  32768
    ushort* h0b  = wl1 + 32768;                 // N*32
    ushort* nidb = h0b  + (size_t)NN * 32;      // N*128 (row-major)
    ushort* hwb  = nidb + (size_t)NN * 128;     // [4][N][32] phase-major
    ushort* aggb = hwb  + (size_t)NN * 128;     // [4][N][32] phase-major
    ushort* endu = aggb + (size_t)NN * 128;
    unsigned long long* esw = (unsigned long long*)(((uintptr_t)endu + 15) & ~(uintptr_t)15);
    int*   deg   = (int*)(esw + NE);
    int*   off   = deg + NN;
    int*   cursor= off + NN + 1;
    int*   bsum  = cursor + NN;                 // 64

    const int gblocks = (NN + 63) / 64;         // 782
    const int eblocks = (NE + 255) / 256;
    const int gablocks = (NN * 4 + 255) / 256;  // 782

    convert_weights<<<(335872 + 255) / 256, 256, 0, stream>>>(f1W, f2W, gW, fgW, l1W, wt);

    // ---- CSR build (reused by all 6 layers) ----
    hipMemsetAsync(deg, 0, (size_t)NN * sizeof(int), stream);
    hipMemsetAsync(cursor, 0, (size_t)NN * sizeof(int), stream);
    hist_kernel<<<eblocks, 256, 0, stream>>>(edst, deg);
    scan1_kernel<<<SCAN_BLOCKS, 1024, 0, stream>>>(deg, off, bsum);
    scan2_kernel<<<1, 64, 0, stream>>>(bsum);
    scan3_kernel<<<SCAN_BLOCKS, 1024, 0, stream>>>(off, bsum);
    permute_kernel<<<eblocks, 256, 0, stream>>>(esrc, edst, ew, off, cursor, esw);

    // ---- network ----
    preproc_kernel<<<(NN + 255) / 256, 256, 0, stream>>>(x, preW, preb, h0b);
    gemm_mfma<<<gblocks, 128, 0, stream>>>(h0b, 32, wf1, f1b, nidb, NN);
    // fc_in2 + gcn0 : hwb = relu(h0@Wf2+b) @ Wg0
    gemm_fused<<<gblocks, 128, 0, stream>>>(h0b, 32, nullptr, 0, wf2, f2b,
                                            wg, hwb, NN);
    for (int l = 0; l < 6; ++l) {
        for (int p = 0; p < 4; ++p) {
            gather_agg<<<gablocks, 256, 0, stream>>>(
                hwb + (size_t)p * PH, (const int2*)esw, off,
                gb + (size_t)l * 128 + p * 32, aggb + (size_t)p * PH);
        }
        if (l < 5) {
            gemm_fused<<<gblocks, 128, 0, stream>>>(nidb, 128, aggb, 128,
                                                    wfg + (size_t)l * 32768,
                                                    fgb + (size_t)l * 128,
                                                    wg + (size_t)(l + 1) * 16384,
                                                    hwb, NN);
        }
    }
    gemm_last<<<gblocks, 128, 0, stream>>>(nidb, aggb,
                                           wfg + (size_t)5 * 32768,
                                           fgb + (size_t)5 * 128,
                                           wl1, l1b, l2W, l2b, out, NN);
}

// Round 7
// 576.440 us; speedup vs baseline: 1.0365x; 1.0365x over previous
//
#include <hip/hip_runtime.h>
#include <cstddef>
#include <cstdint>

#define NN 50000
#define NE 600000
#define SCAN_BLOCKS ((NN + 1023) / 1024)   // 49

typedef __attribute__((ext_vector_type(8))) short bf16x8;
typedef __attribute__((ext_vector_type(4))) float f32x4;

#define SWZ(x) (((x) ^ ((x) >> 2)) & 3)

__device__ __forceinline__ float bf2f(ushort u) {
    return __uint_as_float(((uint32_t)u) << 16);
}
__device__ __forceinline__ ushort f2bf(float f) {   // round-to-nearest-even
    uint32_t b = __float_as_uint(f);
    return (ushort)((b + 0x7FFF + ((b >> 16) & 1)) >> 16);
}

// ---------------------------------------------------------------- weights->bf16 transposed
// Wt[c][k] layouts: wf1[128][32] wf2[128][32] wg[l][128][128] wfg[l][128][256] wl1[128][256]
__global__ __launch_bounds__(256)
void convert_weights(const float* __restrict__ f1W, const float* __restrict__ f2W,
                     const float* __restrict__ gW, const float* __restrict__ fgW,
                     const float* __restrict__ l1W, ushort* __restrict__ wt)
{
    int i = blockIdx.x * 256 + threadIdx.x;          // 0 .. 335871
    if (i >= 335872) return;
    float v;
    if (i < 4096) {                                  // wf1
        int c = i >> 5, k = i & 31;
        v = f1W[k * 128 + c];
    } else if (i < 8192) {                           // wf2
        int j = i - 4096; int c = j >> 5, k = j & 31;
        v = f2W[k * 128 + c];
    } else if (i < 8192 + 98304) {                   // wg
        int j = i - 8192; int l = j >> 14, r = j & 16383;
        int c = r >> 7, k = r & 127;
        v = gW[l * 16384 + k * 128 + c];
    } else if (i < 8192 + 98304 + 196608) {          // wfg
        int j = i - (8192 + 98304); int l = j >> 15, r = j & 32767;
        int c = r >> 8, k = r & 255;
        v = fgW[l * 32768 + k * 128 + c];
    } else {                                         // wl1
        int j = i - (8192 + 98304 + 196608);
        int c = j >> 8, k = j & 255;
        v = l1W[k * 128 + c];
    }
    wt[i] = f2bf(v);
}

// ---------------------------------------------------------------- preproc (out bf16)
__global__ __launch_bounds__(256)
void preproc_kernel(const float* __restrict__ x, const float* __restrict__ W,
                    const float* __restrict__ b, ushort* __restrict__ out)
{
    __shared__ float Wl[512];
    __shared__ float bl[32];
    int tx = threadIdx.x;
    Wl[tx]       = W[tx];
    Wl[tx + 256] = W[tx + 256];
    if (tx < 32) bl[tx] = b[tx];
    __syncthreads();
    int n = blockIdx.x * 256 + tx;
    if (n >= NN) return;
    float xr[16];
    const float4* xp = (const float4*)(x + (size_t)n * 16);
#pragma unroll
    for (int q = 0; q < 4; ++q) {
        float4 v = xp[q];
        xr[q*4+0]=v.x; xr[q*4+1]=v.y; xr[q*4+2]=v.z; xr[q*4+3]=v.w;
    }
    float acc[32];
#pragma unroll
    for (int c = 0; c < 32; ++c) acc[c] = bl[c];
#pragma unroll
    for (int k = 0; k < 16; ++k)
#pragma unroll
        for (int c = 0; c < 32; ++c)
            acc[c] = fmaf(xr[k], Wl[k*32+c], acc[c]);
    ushort4* op = (ushort4*)(out + (size_t)n * 32);
#pragma unroll
    for (int q = 0; q < 8; ++q) {
        ushort4 v;
        v.x = f2bf(fmaxf(acc[q*4+0], 0.f));
        v.y = f2bf(fmaxf(acc[q*4+1], 0.f));
        v.z = f2bf(fmaxf(acc[q*4+2], 0.f));
        v.w = f2bf(fmaxf(acc[q*4+3], 0.f));
        op[q] = v;
    }
}

// ---------------------------------------------------------------- plain MFMA GEMM (fc_in1)
__global__ __launch_bounds__(128)
void gemm_mfma(const ushort* __restrict__ A1, int K1,
               const ushort* __restrict__ Wt, const float* __restrict__ bias,
               ushort* __restrict__ out, int nrows)
{
    __shared__ ushort Atile[64 * 32];
    __shared__ ushort Btile[128 * 32];
    const int tx   = threadIdx.x;
    const int wave = tx >> 6;
    const int lane = tx & 63;
    const int bm   = blockIdx.x * 64;
    const int Ktot = K1;

    const int rs  = lane >> 2;
    const int chn = (lane & 3) ^ SWZ(rs);
    const int m    = lane & 15;
    const int quad = lane >> 4;
    const int slot = quad ^ SWZ(m);

    f32x4 acc0[8], acc1[8];
#pragma unroll
    for (int t = 0; t < 8; ++t) {
        acc0[t] = (f32x4){0.f, 0.f, 0.f, 0.f};
        acc1[t] = (f32x4){0.f, 0.f, 0.f, 0.f};
    }

    for (int kk = 0; kk < Ktot; kk += 32) {
#pragma unroll
        for (int i = 0; i < 2; ++i) {
            int seg = wave + 2 * i;
            int row = seg * 16 + rs;
            int ar  = bm + row; if (ar >= nrows) ar = nrows - 1;
            __builtin_amdgcn_global_load_lds(
                (const __attribute__((address_space(1))) void*)
                    (A1 + (size_t)ar * K1 + kk + chn * 8),
                (__attribute__((address_space(3))) void*)(Atile + seg * 512),
                16, 0, 0);
        }
#pragma unroll
        for (int i = 0; i < 4; ++i) {
            int seg = wave + 2 * i;
            int col = seg * 16 + rs;
            __builtin_amdgcn_global_load_lds(
                (const __attribute__((address_space(1))) void*)
                    (Wt + (size_t)col * Ktot + kk + chn * 8),
                (__attribute__((address_space(3))) void*)(Btile + seg * 512),
                16, 0, 0);
        }
        __syncthreads();
        bf16x8 af0 = *(const bf16x8*)(Atile + (wave * 32 + m) * 32 + slot * 8);
        bf16x8 af1 = *(const bf16x8*)(Atile + (wave * 32 + 16 + m) * 32 + slot * 8);
#pragma unroll
        for (int t = 0; t < 8; ++t) {
            bf16x8 bfr = *(const bf16x8*)(Btile + (t * 16 + m) * 32 + slot * 8);
            acc0[t] = __builtin_amdgcn_mfma_f32_16x16x32_bf16(af0, bfr, acc0[t], 0, 0, 0);
            acc1[t] = __builtin_amdgcn_mfma_f32_16x16x32_bf16(af1, bfr, acc1[t], 0, 0, 0);
        }
        __syncthreads();
    }

#pragma unroll
    for (int half = 0; half < 2; ++half) {
        const int orow0 = bm + wave * 32 + half * 16 + quad * 4;
#pragma unroll
        for (int t = 0; t < 8; ++t) {
            int col = t * 16 + m;
            float bb = bias[col];
            f32x4 a = half ? acc1[t] : acc0[t];
#pragma unroll
            for (int r = 0; r < 4; ++r) {
                int row = orow0 + r;
                if (row < nrows)
                    out[(size_t)row * 128 + col] = f2bf(fmaxf(a[r] + bb, 0.f));
            }
        }
    }
}

// ---------------------------------------------------------------- fused GEMM
// X = relu([A1|A2] @ Wt^T + bias)   (64 rows in LDS, swizzled A-layout)
// out_hw = X @ Wg^T                 (K=128, no bias/act). All row-major.
__global__ __launch_bounds__(128)
void gemm_fused(const ushort* __restrict__ A1, int K1,
                const ushort* __restrict__ A2, int K2,
                const ushort* __restrict__ Wt, const float* __restrict__ bias,
                const ushort* __restrict__ Wg,
                ushort* __restrict__ out_hw, int nrows)
{
    __shared__ ushort Atile[64 * 32];
    __shared__ ushort Btile[128 * 32];
    __shared__ ushort Xt[64 * 128];
    const int tx   = threadIdx.x;
    const int wave = tx >> 6;
    const int lane = tx & 63;
    const int bm   = blockIdx.x * 64;
    const int Ktot = K1 + K2;

    const int rs  = lane >> 2;
    const int chn = (lane & 3) ^ SWZ(rs);
    const int m    = lane & 15;
    const int quad = lane >> 4;
    const int slot = quad ^ SWZ(m);

    f32x4 acc0[8], acc1[8];
#pragma unroll
    for (int t = 0; t < 8; ++t) {
        acc0[t] = (f32x4){0.f, 0.f, 0.f, 0.f};
        acc1[t] = (f32x4){0.f, 0.f, 0.f, 0.f};
    }

    // ---- stage 1 ----
    for (int kk = 0; kk < Ktot; kk += 32) {
        const ushort* asrc; int astr, kl;
        if (kk < K1) { asrc = A1; astr = K1; kl = kk; }
        else         { asrc = A2; astr = K2; kl = kk - K1; }
#pragma unroll
        for (int i = 0; i < 2; ++i) {
            int seg = wave + 2 * i;
            int row = seg * 16 + rs;
            int ar  = bm + row; if (ar >= nrows) ar = nrows - 1;
            __builtin_amdgcn_global_load_lds(
                (const __attribute__((address_space(1))) void*)
                    (asrc + (size_t)ar * astr + kl + chn * 8),
                (__attribute__((address_space(3))) void*)(Atile + seg * 512),
                16, 0, 0);
        }
#pragma unroll
        for (int i = 0; i < 4; ++i) {
            int seg = wave + 2 * i;
            int col = seg * 16 + rs;
            __builtin_amdgcn_global_load_lds(
                (const __attribute__((address_space(1))) void*)
                    (Wt + (size_t)col * Ktot + kk + chn * 8),
                (__attribute__((address_space(3))) void*)(Btile + seg * 512),
                16, 0, 0);
        }
        __syncthreads();
        bf16x8 af0 = *(const bf16x8*)(Atile + (wave * 32 + m) * 32 + slot * 8);
        bf16x8 af1 = *(const bf16x8*)(Atile + (wave * 32 + 16 + m) * 32 + slot * 8);
#pragma unroll
        for (int t = 0; t < 8; ++t) {
            bf16x8 bfr = *(const bf16x8*)(Btile + (t * 16 + m) * 32 + slot * 8);
            acc0[t] = __builtin_amdgcn_mfma_f32_16x16x32_bf16(af0, bfr, acc0[t], 0, 0, 0);
            acc1[t] = __builtin_amdgcn_mfma_f32_16x16x32_bf16(af1, bfr, acc1[t], 0, 0, 0);
        }
        __syncthreads();
    }

    // ---- epilogue 1: bias+relu -> Xt (swizzled A-layout), zero acc ----
#pragma unroll
    for (int half = 0; half < 2; ++half) {
        int rbase = wave * 32 + half * 16 + quad * 4;
#pragma unroll
        for (int t = 0; t < 8; ++t) {
            int col = t * 16 + m;
            float bb = bias[col];
            int c32 = col >> 5, within = col & 7, ks = (col >> 3) & 3;
            f32x4 a = half ? acc1[t] : acc0[t];
#pragma unroll
            for (int r = 0; r < 4; ++r) {
                int row = rbase + r;
                int pos = ks ^ SWZ(row & 15);
                Xt[row * 128 + c32 * 32 + pos * 8 + within] =
                    f2bf(fmaxf(a[r] + bb, 0.f));
            }
        }
    }
#pragma unroll
    for (int t = 0; t < 8; ++t) {
        acc0[t] = (f32x4){0.f, 0.f, 0.f, 0.f};
        acc1[t] = (f32x4){0.f, 0.f, 0.f, 0.f};
    }
    __syncthreads();

    // ---- stage 2: out_hw = X @ Wg^T (K=128) ----
    for (int c32 = 0; c32 < 4; ++c32) {
        int kk = c32 * 32;
#pragma unroll
        for (int i = 0; i < 4; ++i) {
            int seg = wave + 2 * i;
            int col = seg * 16 + rs;
            __builtin_amdgcn_global_load_lds(
                (const __attribute__((address_space(1))) void*)
                    (Wg + (size_t)col * 128 + kk + chn * 8),
                (__attribute__((address_space(3))) void*)(Btile + seg * 512),
                16, 0, 0);
        }
        __syncthreads();
        bf16x8 af0 = *(const bf16x8*)(Xt + (wave * 32 + m) * 128 + kk + slot * 8);
        bf16x8 af1 = *(const bf16x8*)(Xt + (wave * 32 + 16 + m) * 128 + kk + slot * 8);
#pragma unroll
        for (int t = 0; t < 8; ++t) {
            bf16x8 bfr = *(const bf16x8*)(Btile + (t * 16 + m) * 32 + slot * 8);
            acc0[t] = __builtin_amdgcn_mfma_f32_16x16x32_bf16(af0, bfr, acc0[t], 0, 0, 0);
            acc1[t] = __builtin_amdgcn_mfma_f32_16x16x32_bf16(af1, bfr, acc1[t], 0, 0, 0);
        }
        __syncthreads();
    }

    // ---- epilogue 2 ----
#pragma unroll
    for (int half = 0; half < 2; ++half) {
        const int orow0 = bm + wave * 32 + half * 16 + quad * 4;
#pragma unroll
        for (int t = 0; t < 8; ++t) {
            int col = t * 16 + m;
            f32x4 a = half ? acc1[t] : acc0[t];
#pragma unroll
            for (int r = 0; r < 4; ++r) {
                int row = orow0 + r;
                if (row < nrows)
                    out_hw[(size_t)row * 128 + col] = f2bf(a[r]);
            }
        }
    }
}

// ---------------------------------------------------------------- last fused
// X = relu(nid@Wfg5_t + agg@Wfg5_b + b5); HH = relu(nid@l1t + X@l1b + l1bias);
// out = sigmoid(HH @ l2W + l2b)  (fp32, direct to d_out)
__global__ __launch_bounds__(128)
void gemm_last(const ushort* __restrict__ nid, const ushort* __restrict__ agg,
               const ushort* __restrict__ Wt, const float* __restrict__ bias5,
               const ushort* __restrict__ Wl1, const float* __restrict__ l1b,
               const float* __restrict__ l2W, const float* __restrict__ l2b,
               float* __restrict__ out, int nrows)
{
    __shared__ ushort Atile[64 * 32];
    __shared__ ushort Btile[128 * 32];
    __shared__ ushort Xt[64 * 128];
    __shared__ float  w2s[256];
    const int tx   = threadIdx.x;
    const int wave = tx >> 6;
    const int lane = tx & 63;
    const int bm   = blockIdx.x * 64;

    w2s[tx]       = l2W[tx];
    w2s[tx + 128] = l2W[tx + 128];

    const int rs  = lane >> 2;
    const int chn = (lane & 3) ^ SWZ(rs);
    const int m    = lane & 15;
    const int quad = lane >> 4;
    const int slot = quad ^ SWZ(m);

    f32x4 acc0[8], acc1[8];
#pragma unroll
    for (int t = 0; t < 8; ++t) {
        acc0[t] = (f32x4){0.f, 0.f, 0.f, 0.f};
        acc1[t] = (f32x4){0.f, 0.f, 0.f, 0.f};
    }

    // ---- stage 1: X = relu(nid@t + agg@b + b5), Ktot=256 ----
    for (int kk = 0; kk < 256; kk += 32) {
        const ushort* asrc; int kl;
        if (kk < 128) { asrc = nid; kl = kk; }
        else          { asrc = agg; kl = kk - 128; }
#pragma unroll
        for (int i = 0; i < 2; ++i) {
            int seg = wave + 2 * i;
            int row = seg * 16 + rs;
            int ar  = bm + row; if (ar >= nrows) ar = nrows - 1;
            __builtin_amdgcn_global_load_lds(
                (const __attribute__((address_space(1))) void*)
                    (asrc + (size_t)ar * 128 + kl + chn * 8),
                (__attribute__((address_space(3))) void*)(Atile + seg * 512),
                16, 0, 0);
        }
#pragma unroll
        for (int i = 0; i < 4; ++i) {
            int seg = wave + 2 * i;
            int col = seg * 16 + rs;
            __builtin_amdgcn_global_load_lds(
                (const __attribute__((address_space(1))) void*)
                    (Wt + (size_t)col * 256 + kk + chn * 8),
                (__attribute__((address_space(3))) void*)(Btile + seg * 512),
                16, 0, 0);
        }
        __syncthreads();
        bf16x8 af0 = *(const bf16x8*)(Atile + (wave * 32 + m) * 32 + slot * 8);
        bf16x8 af1 = *(const bf16x8*)(Atile + (wave * 32 + 16 + m) * 32 + slot * 8);
#pragma unroll
        for (int t = 0; t < 8; ++t) {
            bf16x8 bfr = *(const bf16x8*)(Btile + (t * 16 + m) * 32 + slot * 8);
            acc0[t] = __builtin_amdgcn_mfma_f32_16x16x32_bf16(af0, bfr, acc0[t], 0, 0, 0);
            acc1[t] = __builtin_amdgcn_mfma_f32_16x16x32_bf16(af1, bfr, acc1[t], 0, 0, 0);
        }
        __syncthreads();
    }

    // ---- epilogue 1 -> Xt ----
#pragma unroll
    for (int half = 0; half < 2; ++half) {
        int rbase = wave * 32 + half * 16 + quad * 4;
#pragma unroll
        for (int t = 0; t < 8; ++t) {
            int col = t * 16 + m;
            float bb = bias5[col];
            int c32 = col >> 5, within = col & 7, ks = (col >> 3) & 3;
            f32x4 a = half ? acc1[t] : acc0[t];
#pragma unroll
            for (int r = 0; r < 4; ++r) {
                int row = rbase + r;
                int pos = ks ^ SWZ(row & 15);
                Xt[row * 128 + c32 * 32 + pos * 8 + within] =
                    f2bf(fmaxf(a[r] + bb, 0.f));
            }
        }
    }
#pragma unroll
    for (int t = 0; t < 8; ++t) {
        acc0[t] = (f32x4){0.f, 0.f, 0.f, 0.f};
        acc1[t] = (f32x4){0.f, 0.f, 0.f, 0.f};
    }
    __syncthreads();

    // ---- stage 2: HH = nid@l1t + X@l1b, Ktot=256 ----
    for (int c8 = 0; c8 < 8; ++c8) {
        int kk = c8 * 32;
        if (c8 < 4) {
#pragma unroll
            for (int i = 0; i < 2; ++i) {
                int seg = wave + 2 * i;
                int row = seg * 16 + rs;
                int ar  = bm + row; if (ar >= nrows) ar = nrows - 1;
                __builtin_amdgcn_global_load_lds(
                    (const __attribute__((address_space(1))) void*)
                        (nid + (size_t)ar * 128 + kk + chn * 8),
                    (__attribute__((address_space(3))) void*)(Atile + seg * 512),
                    16, 0, 0);
            }
        }
#pragma unroll
        for (int i = 0; i < 4; ++i) {
            int seg = wave + 2 * i;
            int col = seg * 16 + rs;
            __builtin_amdgcn_global_load_lds(
                (const __attribute__((address_space(1))) void*)
                    (Wl1 + (size_t)col * 256 + kk + chn * 8),
                (__attribute__((address_space(3))) void*)(Btile + seg * 512),
                16, 0, 0);
        }
        __syncthreads();
        bf16x8 af0, af1;
        if (c8 < 4) {
            af0 = *(const bf16x8*)(Atile + (wave * 32 + m) * 32 + slot * 8);
            af1 = *(const bf16x8*)(Atile + (wave * 32 + 16 + m) * 32 + slot * 8);
        } else {
            int ko = (c8 - 4) * 32;
            af0 = *(const bf16x8*)(Xt + (wave * 32 + m) * 128 + ko + slot * 8);
            af1 = *(const bf16x8*)(Xt + (wave * 32 + 16 + m) * 128 + ko + slot * 8);
        }
#pragma unroll
        for (int t = 0; t < 8; ++t) {
            bf16x8 bfr = *(const bf16x8*)(Btile + (t * 16 + m) * 32 + slot * 8);
            acc0[t] = __builtin_amdgcn_mfma_f32_16x16x32_bf16(af0, bfr, acc0[t], 0, 0, 0);
            acc1[t] = __builtin_amdgcn_mfma_f32_16x16x32_bf16(af1, bfr, acc1[t], 0, 0, 0);
        }
        __syncthreads();
    }

    // ---- epilogue: relu(HH+l1b) @ l2W, sigmoid, write fp32 out ----
    float bb[8];
#pragma unroll
    for (int t = 0; t < 8; ++t) bb[t] = l1b[t * 16 + m];
    float b20 = l2b[0], b21 = l2b[1];
#pragma unroll
    for (int half = 0; half < 2; ++half) {
#pragma unroll
        for (int r = 0; r < 4; ++r) {
            float p0 = 0.f, p1 = 0.f;
#pragma unroll
            for (int t = 0; t < 8; ++t) {
                int col = t * 16 + m;
                f32x4 a = half ? acc1[t] : acc0[t];
                float v = fmaxf(a[r] + bb[t], 0.f);
                p0 = fmaf(v, w2s[col * 2 + 0], p0);
                p1 = fmaf(v, w2s[col * 2 + 1], p1);
            }
#pragma unroll
            for (int mask = 1; mask < 16; mask <<= 1) {
                p0 += __shfl_xor(p0, mask);
                p1 += __shfl_xor(p1, mask);
            }
            if (m == 0) {
                int row = bm + wave * 32 + half * 16 + quad * 4 + r;
                if (row < nrows) {
                    out[(size_t)row * 2 + 0] = 1.f / (1.f + __expf(-(p0 + b20)));
                    out[(size_t)row * 2 + 1] = 1.f / (1.f + __expf(-(p1 + b21)));
                }
            }
        }
    }
}

// ---------------------------------------------------------------- CSR build
__global__ __launch_bounds__(256)
void hist_kernel(const int* __restrict__ dst, int* __restrict__ deg)
{
    int e = blockIdx.x * 256 + threadIdx.x;
    if (e < NE) atomicAdd(&deg[dst[e]], 1);
}

__global__ __launch_bounds__(1024)
void scan1_kernel(const int* __restrict__ deg, int* __restrict__ off,
                  int* __restrict__ bsum)
{
    __shared__ int buf[1024];
    int tx = threadIdx.x;
    int i = blockIdx.x * 1024 + tx;
    int v = (i < NN) ? deg[i] : 0;
    buf[tx] = v;
    __syncthreads();
    for (int s = 1; s < 1024; s <<= 1) {
        int t = (tx >= s) ? buf[tx - s] : 0;
        __syncthreads();
        buf[tx] += t;
        __syncthreads();
    }
    if (i < NN) off[i] = buf[tx] - v;
    if (tx == 1023) bsum[blockIdx.x] = buf[1023];
}

__global__ __launch_bounds__(64)
void scan2_kernel(int* __restrict__ bsum)
{
    __shared__ int buf[64];
    int tx = threadIdx.x;
    int v = (tx < SCAN_BLOCKS) ? bsum[tx] : 0;
    buf[tx] = v;
    __syncthreads();
    for (int s = 1; s < 64; s <<= 1) {
        int t = (tx >= s) ? buf[tx - s] : 0;
        __syncthreads();
        buf[tx] += t;
        __syncthreads();
    }
    if (tx < SCAN_BLOCKS) bsum[tx] = buf[tx] - v;
}

__global__ __launch_bounds__(1024)
void scan3_kernel(int* __restrict__ off, const int* __restrict__ bsum)
{
    int i = blockIdx.x * 1024 + threadIdx.x;
    if (i < NN) off[i] += bsum[blockIdx.x];
    if (i == 0) off[NN] = NE;
}

__global__ __launch_bounds__(256)
void permute_kernel(const int* __restrict__ src, const int* __restrict__ dst,
                    const float* __restrict__ w, const int* __restrict__ off,
                    int* __restrict__ cursor, unsigned long long* __restrict__ esw)
{
    int e = blockIdx.x * 256 + threadIdx.x;
    if (e >= NE) return;
    int d = dst[e];
    int p = off[d] + atomicAdd(&cursor[d], 1);
    unsigned long long packed = (unsigned int)src[e] |
        ((unsigned long long)(unsigned int)__float_as_uint(w[e]) << 32);
    __builtin_nontemporal_store(packed, &esw[p]);
}

// ---------------------------------------------------------------- gather agg (wave/node)
// One wave per node. Per edge: ONE coalesced global_load_dword covers the full
// 128-ch bf16 row (lane i -> channels 2i,2i+1). Edge (src,w) staged 64-at-a-time
// into lanes, broadcast per edge via readlane (scalar operands).
// agg[n][c] = bf16(relu(sum_e w*hw[src][c] + gbias[c]))
__global__ __launch_bounds__(256)
void gather_agg(const ushort* __restrict__ hw,
                const unsigned long long* __restrict__ esw,
                const int* __restrict__ off, const float* __restrict__ gbias,
                ushort* __restrict__ agg)
{
    const int wid  = blockIdx.x * 4 + (threadIdx.x >> 6);   // node id
    const int lane = threadIdx.x & 63;
    if (wid >= NN) return;
    const int e0 = off[wid], e1 = off[wid + 1];
    float a0 = 0.f, a1 = 0.f;
    const ushort* hp = hw + lane * 2;
    for (int base = e0; base < e1; base += 64) {
        int idx = base + lane;
        unsigned long long pk = (idx < e1) ? esw[idx] : 0ULL;
        int slo = (int)(unsigned int)(pk & 0xffffffffULL);
        int shi = (int)(unsigned int)(pk >> 32);
        int cnt = e1 - base; if (cnt > 64) cnt = 64;
#pragma unroll 4
        for (int j = 0; j < cnt; ++j) {
            int   s = __builtin_amdgcn_readlane(slo, j);
            float w = __int_as_float(__builtin_amdgcn_readlane(shi, j));
            unsigned int rv = *(const unsigned int*)(hp + (size_t)s * 128);
            a0 = fmaf(bf2f((ushort)(rv & 0xffff)), w, a0);
            a1 = fmaf(bf2f((ushort)(rv >> 16)),    w, a1);
        }
    }
    float b0 = gbias[lane * 2], b1 = gbias[lane * 2 + 1];
    unsigned int o = (unsigned int)f2bf(fmaxf(a0 + b0, 0.f)) |
                     ((unsigned int)f2bf(fmaxf(a1 + b1, 0.f)) << 16);
    *(unsigned int*)(agg + (size_t)wid * 128 + lane * 2) = o;
}

// ---------------------------------------------------------------- launch
extern "C" void kernel_launch(void* const* d_in, const int* in_sizes, int n_in,
                              void* d_out, int out_size, void* d_ws, size_t ws_size,
                              hipStream_t stream)
{
    const float* x    = (const float*)d_in[0];
    const int*   esrc = (const int*)  d_in[1];
    const int*   edst = (const int*)  d_in[2];
    const float* ew   = (const float*)d_in[3];
    const float* preW = (const float*)d_in[4];
    const float* preb = (const float*)d_in[5];
    const float* f1W  = (const float*)d_in[6];
    const float* f1b  = (const float*)d_in[7];
    const float* f2W  = (const float*)d_in[8];
    const float* f2b  = (const float*)d_in[9];
    const float* gW   = (const float*)d_in[10];
    const float* gb   = (const float*)d_in[11];
    const float* fgW  = (const float*)d_in[12];
    const float* fgb  = (const float*)d_in[13];
    const float* l1W  = (const float*)d_in[14];
    const float* l1b  = (const float*)d_in[15];
    const float* l2W  = (const float*)d_in[16];
    const float* l2b  = (const float*)d_in[17];
    float* out = (float*)d_out;

    ushort* wt   = (ushort*)d_ws;
    ushort* wf1  = wt;                          //   4096
    ushort* wf2  = wf1 + 4096;                  //   4096
    ushort* wg   = wf2 + 4096;                  //  98304
    ushort* wfg  = wg  + 98304;                 // 196608
    ushort* wl1  = wfg + 196608;                //  32768
    ushort* h0b  = wl1 + 32768;                 // N*32
    ushort* nidb = h0b  + (size_t)NN * 32;      // N*128
    ushort* hwb  = nidb + (size_t)NN * 128;     // N*128 row-major
    ushort* aggb = hwb  + (size_t)NN * 128;     // N*128 row-major
    ushort* endu = aggb + (size_t)NN * 128;
    unsigned long long* esw = (unsigned long long*)(((uintptr_t)endu + 15) & ~(uintptr_t)15);
    int*   deg   = (int*)(esw + NE);
    int*   off   = deg + NN;
    int*   cursor= off + NN + 1;
    int*   bsum  = cursor + NN;                 // 64

    const int gblocks = (NN + 63) / 64;         // 782
    const int eblocks = (NE + 255) / 256;
    const int wblocks = (NN + 3) / 4;           // 12500 (4 waves/block)

    convert_weights<<<(335872 + 255) / 256, 256, 0, stream>>>(f1W, f2W, gW, fgW, l1W, wt);

    // ---- CSR build (reused by all 6 layers) ----
    hipMemsetAsync(deg, 0, (size_t)NN * sizeof(int), stream);
    hipMemsetAsync(cursor, 0, (size_t)NN * sizeof(int), stream);
    hist_kernel<<<eblocks, 256, 0, stream>>>(edst, deg);
    scan1_kernel<<<SCAN_BLOCKS, 1024, 0, stream>>>(deg, off, bsum);
    scan2_kernel<<<1, 64, 0, stream>>>(bsum);
    scan3_kernel<<<SCAN_BLOCKS, 1024, 0, stream>>>(off, bsum);
    permute_kernel<<<eblocks, 256, 0, stream>>>(esrc, edst, ew, off, cursor, esw);

    // ---- network ----
    preproc_kernel<<<(NN + 255) / 256, 256, 0, stream>>>(x, preW, preb, h0b);
    gemm_mfma<<<gblocks, 128, 0, stream>>>(h0b, 32, wf1, f1b, nidb, NN);
    // fc_in2 + gcn0 : hwb = relu(h0@Wf2+b) @ Wg0
    gemm_fused<<<gblocks, 128, 0, stream>>>(h0b, 32, nullptr, 0, wf2, f2b,
                                            wg, hwb, NN);
    for (int l = 0; l < 6; ++l) {
        gather_agg<<<wblocks, 256, 0, stream>>>(hwb, esw, off,
                                                gb + (size_t)l * 128, aggb);
        if (l < 5) {
            gemm_fused<<<gblocks, 128, 0, stream>>>(nidb, 128, aggb, 128,
                                                    wfg + (size_t)l * 32768,
                                                    fgb + (size_t)l * 128,
                                                    wg + (size_t)(l + 1) * 16384,
                                                    hwb, NN);
        }
    }
    gemm_last<<<gblocks, 128, 0, stream>>>(nidb, aggb,
                                           wfg + (size_t)5 * 32768,
                                           fgb + (size_t)5 * 128,
                                           wl1, l1b, l2W, l2b, out, NN);
}

// Round 8
// 462.296 us; speedup vs baseline: 1.2925x; 1.2469x over previous
//
#include <hip/hip_runtime.h>
#include <cstddef>
#include <cstdint>

#define NN 50000
#define NE 600000
#define SCAN_BLOCKS ((NN + 1023) / 1024)   // 49

typedef __attribute__((ext_vector_type(8))) short bf16x8;
typedef __attribute__((ext_vector_type(4))) float f32x4;

#define SWZ(x) (((x) ^ ((x) >> 2)) & 3)

__device__ __forceinline__ float bf2f(ushort u) {
    return __uint_as_float(((uint32_t)u) << 16);
}
__device__ __forceinline__ ushort f2bf(float f) {   // round-to-nearest-even
    uint32_t b = __float_as_uint(f);
    return (ushort)((b + 0x7FFF + ((b >> 16) & 1)) >> 16);
}

// ---------------------------------------------------------------- weights->bf16 transposed
// Wt[c][k] layouts: wf1[128][32] wf2[128][32] wg[l][128][128] wfg[l][128][256] wl1[128][256]
__global__ __launch_bounds__(256)
void convert_weights(const float* __restrict__ f1W, const float* __restrict__ f2W,
                     const float* __restrict__ gW, const float* __restrict__ fgW,
                     const float* __restrict__ l1W, ushort* __restrict__ wt)
{
    int i = blockIdx.x * 256 + threadIdx.x;          // 0 .. 335871
    if (i >= 335872) return;
    float v;
    if (i < 4096) {                                  // wf1
        int c = i >> 5, k = i & 31;
        v = f1W[k * 128 + c];
    } else if (i < 8192) {                           // wf2
        int j = i - 4096; int c = j >> 5, k = j & 31;
        v = f2W[k * 128 + c];
    } else if (i < 8192 + 98304) {                   // wg
        int j = i - 8192; int l = j >> 14, r = j & 16383;
        int c = r >> 7, k = r & 127;
        v = gW[l * 16384 + k * 128 + c];
    } else if (i < 8192 + 98304 + 196608) {          // wfg
        int j = i - (8192 + 98304); int l = j >> 15, r = j & 32767;
        int c = r >> 8, k = r & 255;
        v = fgW[l * 32768 + k * 128 + c];
    } else {                                         // wl1
        int j = i - (8192 + 98304 + 196608);
        int c = j >> 8, k = j & 255;
        v = l1W[k * 128 + c];
    }
    wt[i] = f2bf(v);
}

// ---------------------------------------------------------------- preproc (out bf16)
__global__ __launch_bounds__(256)
void preproc_kernel(const float* __restrict__ x, const float* __restrict__ W,
                    const float* __restrict__ b, ushort* __restrict__ out)
{
    __shared__ float Wl[512];
    __shared__ float bl[32];
    int tx = threadIdx.x;
    Wl[tx]       = W[tx];
    Wl[tx + 256] = W[tx + 256];
    if (tx < 32) bl[tx] = b[tx];
    __syncthreads();
    int n = blockIdx.x * 256 + tx;
    if (n >= NN) return;
    float xr[16];
    const float4* xp = (const float4*)(x + (size_t)n * 16);
#pragma unroll
    for (int q = 0; q < 4; ++q) {
        float4 v = xp[q];
        xr[q*4+0]=v.x; xr[q*4+1]=v.y; xr[q*4+2]=v.z; xr[q*4+3]=v.w;
    }
    float acc[32];
#pragma unroll
    for (int c = 0; c < 32; ++c) acc[c] = bl[c];
#pragma unroll
    for (int k = 0; k < 16; ++k)
#pragma unroll
        for (int c = 0; c < 32; ++c)
            acc[c] = fmaf(xr[k], Wl[k*32+c], acc[c]);
    ushort4* op = (ushort4*)(out + (size_t)n * 32);
#pragma unroll
    for (int q = 0; q < 8; ++q) {
        ushort4 v;
        v.x = f2bf(fmaxf(acc[q*4+0], 0.f));
        v.y = f2bf(fmaxf(acc[q*4+1], 0.f));
        v.z = f2bf(fmaxf(acc[q*4+2], 0.f));
        v.w = f2bf(fmaxf(acc[q*4+3], 0.f));
        op[q] = v;
    }
}

// ---------------------------------------------------------------- plain MFMA GEMM (fc_in1)
__global__ __launch_bounds__(128)
void gemm_mfma(const ushort* __restrict__ A1, int K1,
               const ushort* __restrict__ Wt, const float* __restrict__ bias,
               ushort* __restrict__ out, int nrows)
{
    __shared__ ushort Atile[64 * 32];
    __shared__ ushort Btile[128 * 32];
    const int tx   = threadIdx.x;
    const int wave = tx >> 6;
    const int lane = tx & 63;
    const int bm   = blockIdx.x * 64;
    const int Ktot = K1;

    const int rs  = lane >> 2;
    const int chn = (lane & 3) ^ SWZ(rs);
    const int m    = lane & 15;
    const int quad = lane >> 4;
    const int slot = quad ^ SWZ(m);

    f32x4 acc0[8], acc1[8];
#pragma unroll
    for (int t = 0; t < 8; ++t) {
        acc0[t] = (f32x4){0.f, 0.f, 0.f, 0.f};
        acc1[t] = (f32x4){0.f, 0.f, 0.f, 0.f};
    }

    for (int kk = 0; kk < Ktot; kk += 32) {
#pragma unroll
        for (int i = 0; i < 2; ++i) {
            int seg = wave + 2 * i;
            int row = seg * 16 + rs;
            int ar  = bm + row; if (ar >= nrows) ar = nrows - 1;
            __builtin_amdgcn_global_load_lds(
                (const __attribute__((address_space(1))) void*)
                    (A1 + (size_t)ar * K1 + kk + chn * 8),
                (__attribute__((address_space(3))) void*)(Atile + seg * 512),
                16, 0, 0);
        }
#pragma unroll
        for (int i = 0; i < 4; ++i) {
            int seg = wave + 2 * i;
            int col = seg * 16 + rs;
            __builtin_amdgcn_global_load_lds(
                (const __attribute__((address_space(1))) void*)
                    (Wt + (size_t)col * Ktot + kk + chn * 8),
                (__attribute__((address_space(3))) void*)(Btile + seg * 512),
                16, 0, 0);
        }
        __syncthreads();
        bf16x8 af0 = *(const bf16x8*)(Atile + (wave * 32 + m) * 32 + slot * 8);
        bf16x8 af1 = *(const bf16x8*)(Atile + (wave * 32 + 16 + m) * 32 + slot * 8);
#pragma unroll
        for (int t = 0; t < 8; ++t) {
            bf16x8 bfr = *(const bf16x8*)(Btile + (t * 16 + m) * 32 + slot * 8);
            acc0[t] = __builtin_amdgcn_mfma_f32_16x16x32_bf16(af0, bfr, acc0[t], 0, 0, 0);
            acc1[t] = __builtin_amdgcn_mfma_f32_16x16x32_bf16(af1, bfr, acc1[t], 0, 0, 0);
        }
        __syncthreads();
    }

#pragma unroll
    for (int half = 0; half < 2; ++half) {
        const int orow0 = bm + wave * 32 + half * 16 + quad * 4;
#pragma unroll
        for (int t = 0; t < 8; ++t) {
            int col = t * 16 + m;
            float bb = bias[col];
            f32x4 a = half ? acc1[t] : acc0[t];
#pragma unroll
            for (int r = 0; r < 4; ++r) {
                int row = orow0 + r;
                if (row < nrows)
                    out[(size_t)row * 128 + col] = f2bf(fmaxf(a[r] + bb, 0.f));
            }
        }
    }
}

// ---------------------------------------------------------------- fused GEMM
// X = relu([A1|A2] @ Wt^T + bias)   (64 rows in LDS, swizzled A-layout)
// out_hw = X @ Wg^T                 (K=128, no bias/act). All row-major.
__global__ __launch_bounds__(128)
void gemm_fused(const ushort* __restrict__ A1, int K1,
                const ushort* __restrict__ A2, int K2,
                const ushort* __restrict__ Wt, const float* __restrict__ bias,
                const ushort* __restrict__ Wg,
                ushort* __restrict__ out_hw, int nrows)
{
    __shared__ ushort Atile[64 * 32];
    __shared__ ushort Btile[128 * 32];
    __shared__ ushort Xt[64 * 128];
    const int tx   = threadIdx.x;
    const int wave = tx >> 6;
    const int lane = tx & 63;
    const int bm   = blockIdx.x * 64;
    const int Ktot = K1 + K2;

    const int rs  = lane >> 2;
    const int chn = (lane & 3) ^ SWZ(rs);
    const int m    = lane & 15;
    const int quad = lane >> 4;
    const int slot = quad ^ SWZ(m);

    f32x4 acc0[8], acc1[8];
#pragma unroll
    for (int t = 0; t < 8; ++t) {
        acc0[t] = (f32x4){0.f, 0.f, 0.f, 0.f};
        acc1[t] = (f32x4){0.f, 0.f, 0.f, 0.f};
    }

    // ---- stage 1 ----
    for (int kk = 0; kk < Ktot; kk += 32) {
        const ushort* asrc; int astr, kl;
        if (kk < K1) { asrc = A1; astr = K1; kl = kk; }
        else         { asrc = A2; astr = K2; kl = kk - K1; }
#pragma unroll
        for (int i = 0; i < 2; ++i) {
            int seg = wave + 2 * i;
            int row = seg * 16 + rs;
            int ar  = bm + row; if (ar >= nrows) ar = nrows - 1;
            __builtin_amdgcn_global_load_lds(
                (const __attribute__((address_space(1))) void*)
                    (asrc + (size_t)ar * astr + kl + chn * 8),
                (__attribute__((address_space(3))) void*)(Atile + seg * 512),
                16, 0, 0);
        }
#pragma unroll
        for (int i = 0; i < 4; ++i) {
            int seg = wave + 2 * i;
            int col = seg * 16 + rs;
            __builtin_amdgcn_global_load_lds(
                (const __attribute__((address_space(1))) void*)
                    (Wt + (size_t)col * Ktot + kk + chn * 8),
                (__attribute__((address_space(3))) void*)(Btile + seg * 512),
                16, 0, 0);
        }
        __syncthreads();
        bf16x8 af0 = *(const bf16x8*)(Atile + (wave * 32 + m) * 32 + slot * 8);
        bf16x8 af1 = *(const bf16x8*)(Atile + (wave * 32 + 16 + m) * 32 + slot * 8);
#pragma unroll
        for (int t = 0; t < 8; ++t) {
            bf16x8 bfr = *(const bf16x8*)(Btile + (t * 16 + m) * 32 + slot * 8);
            acc0[t] = __builtin_amdgcn_mfma_f32_16x16x32_bf16(af0, bfr, acc0[t], 0, 0, 0);
            acc1[t] = __builtin_amdgcn_mfma_f32_16x16x32_bf16(af1, bfr, acc1[t], 0, 0, 0);
        }
        __syncthreads();
    }

    // ---- epilogue 1: bias+relu -> Xt (swizzled A-layout), zero acc ----
#pragma unroll
    for (int half = 0; half < 2; ++half) {
        int rbase = wave * 32 + half * 16 + quad * 4;
#pragma unroll
        for (int t = 0; t < 8; ++t) {
            int col = t * 16 + m;
            float bb = bias[col];
            int c32 = col >> 5, within = col & 7, ks = (col >> 3) & 3;
            f32x4 a = half ? acc1[t] : acc0[t];
#pragma unroll
            for (int r = 0; r < 4; ++r) {
                int row = rbase + r;
                int pos = ks ^ SWZ(row & 15);
                Xt[row * 128 + c32 * 32 + pos * 8 + within] =
                    f2bf(fmaxf(a[r] + bb, 0.f));
            }
        }
    }
#pragma unroll
    for (int t = 0; t < 8; ++t) {
        acc0[t] = (f32x4){0.f, 0.f, 0.f, 0.f};
        acc1[t] = (f32x4){0.f, 0.f, 0.f, 0.f};
    }
    __syncthreads();

    // ---- stage 2: out_hw = X @ Wg^T (K=128) ----
    for (int c32 = 0; c32 < 4; ++c32) {
        int kk = c32 * 32;
#pragma unroll
        for (int i = 0; i < 4; ++i) {
            int seg = wave + 2 * i;
            int col = seg * 16 + rs;
            __builtin_amdgcn_global_load_lds(
                (const __attribute__((address_space(1))) void*)
                    (Wg + (size_t)col * 128 + kk + chn * 8),
                (__attribute__((address_space(3))) void*)(Btile + seg * 512),
                16, 0, 0);
        }
        __syncthreads();
        bf16x8 af0 = *(const bf16x8*)(Xt + (wave * 32 + m) * 128 + kk + slot * 8);
        bf16x8 af1 = *(const bf16x8*)(Xt + (wave * 32 + 16 + m) * 128 + kk + slot * 8);
#pragma unroll
        for (int t = 0; t < 8; ++t) {
            bf16x8 bfr = *(const bf16x8*)(Btile + (t * 16 + m) * 32 + slot * 8);
            acc0[t] = __builtin_amdgcn_mfma_f32_16x16x32_bf16(af0, bfr, acc0[t], 0, 0, 0);
            acc1[t] = __builtin_amdgcn_mfma_f32_16x16x32_bf16(af1, bfr, acc1[t], 0, 0, 0);
        }
        __syncthreads();
    }

    // ---- epilogue 2 ----
#pragma unroll
    for (int half = 0; half < 2; ++half) {
        const int orow0 = bm + wave * 32 + half * 16 + quad * 4;
#pragma unroll
        for (int t = 0; t < 8; ++t) {
            int col = t * 16 + m;
            f32x4 a = half ? acc1[t] : acc0[t];
#pragma unroll
            for (int r = 0; r < 4; ++r) {
                int row = orow0 + r;
                if (row < nrows)
                    out_hw[(size_t)row * 128 + col] = f2bf(a[r]);
            }
        }
    }
}

// ---------------------------------------------------------------- last fused
// X = relu(nid@Wfg5_t + agg@Wfg5_b + b5); HH = relu(nid@l1t + X@l1b + l1bias);
// out = sigmoid(HH @ l2W + l2b)  (fp32, direct to d_out)
__global__ __launch_bounds__(128)
void gemm_last(const ushort* __restrict__ nid, const ushort* __restrict__ agg,
               const ushort* __restrict__ Wt, const float* __restrict__ bias5,
               const ushort* __restrict__ Wl1, const float* __restrict__ l1b,
               const float* __restrict__ l2W, const float* __restrict__ l2b,
               float* __restrict__ out, int nrows)
{
    __shared__ ushort Atile[64 * 32];
    __shared__ ushort Btile[128 * 32];
    __shared__ ushort Xt[64 * 128];
    __shared__ float  w2s[256];
    const int tx   = threadIdx.x;
    const int wave = tx >> 6;
    const int lane = tx & 63;
    const int bm   = blockIdx.x * 64;

    w2s[tx]       = l2W[tx];
    w2s[tx + 128] = l2W[tx + 128];

    const int rs  = lane >> 2;
    const int chn = (lane & 3) ^ SWZ(rs);
    const int m    = lane & 15;
    const int quad = lane >> 4;
    const int slot = quad ^ SWZ(m);

    f32x4 acc0[8], acc1[8];
#pragma unroll
    for (int t = 0; t < 8; ++t) {
        acc0[t] = (f32x4){0.f, 0.f, 0.f, 0.f};
        acc1[t] = (f32x4){0.f, 0.f, 0.f, 0.f};
    }

    // ---- stage 1: X = relu(nid@t + agg@b + b5), Ktot=256 ----
    for (int kk = 0; kk < 256; kk += 32) {
        const ushort* asrc; int kl;
        if (kk < 128) { asrc = nid; kl = kk; }
        else          { asrc = agg; kl = kk - 128; }
#pragma unroll
        for (int i = 0; i < 2; ++i) {
            int seg = wave + 2 * i;
            int row = seg * 16 + rs;
            int ar  = bm + row; if (ar >= nrows) ar = nrows - 1;
            __builtin_amdgcn_global_load_lds(
                (const __attribute__((address_space(1))) void*)
                    (asrc + (size_t)ar * 128 + kl + chn * 8),
                (__attribute__((address_space(3))) void*)(Atile + seg * 512),
                16, 0, 0);
        }
#pragma unroll
        for (int i = 0; i < 4; ++i) {
            int seg = wave + 2 * i;
            int col = seg * 16 + rs;
            __builtin_amdgcn_global_load_lds(
                (const __attribute__((address_space(1))) void*)
                    (Wt + (size_t)col * 256 + kk + chn * 8),
                (__attribute__((address_space(3))) void*)(Btile + seg * 512),
                16, 0, 0);
        }
        __syncthreads();
        bf16x8 af0 = *(const bf16x8*)(Atile + (wave * 32 + m) * 32 + slot * 8);
        bf16x8 af1 = *(const bf16x8*)(Atile + (wave * 32 + 16 + m) * 32 + slot * 8);
#pragma unroll
        for (int t = 0; t < 8; ++t) {
            bf16x8 bfr = *(const bf16x8*)(Btile + (t * 16 + m) * 32 + slot * 8);
            acc0[t] = __builtin_amdgcn_mfma_f32_16x16x32_bf16(af0, bfr, acc0[t], 0, 0, 0);
            acc1[t] = __builtin_amdgcn_mfma_f32_16x16x32_bf16(af1, bfr, acc1[t], 0, 0, 0);
        }
        __syncthreads();
    }

    // ---- epilogue 1 -> Xt ----
#pragma unroll
    for (int half = 0; half < 2; ++half) {
        int rbase = wave * 32 + half * 16 + quad * 4;
#pragma unroll
        for (int t = 0; t < 8; ++t) {
            int col = t * 16 + m;
            float bb = bias5[col];
            int c32 = col >> 5, within = col & 7, ks = (col >> 3) & 3;
            f32x4 a = half ? acc1[t] : acc0[t];
#pragma unroll
            for (int r = 0; r < 4; ++r) {
                int row = rbase + r;
                int pos = ks ^ SWZ(row & 15);
                Xt[row * 128 + c32 * 32 + pos * 8 + within] =
                    f2bf(fmaxf(a[r] + bb, 0.f));
            }
        }
    }
#pragma unroll
    for (int t = 0; t < 8; ++t) {
        acc0[t] = (f32x4){0.f, 0.f, 0.f, 0.f};
        acc1[t] = (f32x4){0.f, 0.f, 0.f, 0.f};
    }
    __syncthreads();

    // ---- stage 2: HH = nid@l1t + X@l1b, Ktot=256 ----
    for (int c8 = 0; c8 < 8; ++c8) {
        int kk = c8 * 32;
        if (c8 < 4) {
#pragma unroll
            for (int i = 0; i < 2; ++i) {
                int seg = wave + 2 * i;
                int row = seg * 16 + rs;
                int ar  = bm + row; if (ar >= nrows) ar = nrows - 1;
                __builtin_amdgcn_global_load_lds(
                    (const __attribute__((address_space(1))) void*)
                        (nid + (size_t)ar * 128 + kk + chn * 8),
                    (__attribute__((address_space(3))) void*)(Atile + seg * 512),
                    16, 0, 0);
            }
        }
#pragma unroll
        for (int i = 0; i < 4; ++i) {
            int seg = wave + 2 * i;
            int col = seg * 16 + rs;
            __builtin_amdgcn_global_load_lds(
                (const __attribute__((address_space(1))) void*)
                    (Wl1 + (size_t)col * 256 + kk + chn * 8),
                (__attribute__((address_space(3))) void*)(Btile + seg * 512),
                16, 0, 0);
        }
        __syncthreads();
        bf16x8 af0, af1;
        if (c8 < 4) {
            af0 = *(const bf16x8*)(Atile + (wave * 32 + m) * 32 + slot * 8);
            af1 = *(const bf16x8*)(Atile + (wave * 32 + 16 + m) * 32 + slot * 8);
        } else {
            int ko = (c8 - 4) * 32;
            af0 = *(const bf16x8*)(Xt + (wave * 32 + m) * 128 + ko + slot * 8);
            af1 = *(const bf16x8*)(Xt + (wave * 32 + 16 + m) * 128 + ko + slot * 8);
        }
#pragma unroll
        for (int t = 0; t < 8; ++t) {
            bf16x8 bfr = *(const bf16x8*)(Btile + (t * 16 + m) * 32 + slot * 8);
            acc0[t] = __builtin_amdgcn_mfma_f32_16x16x32_bf16(af0, bfr, acc0[t], 0, 0, 0);
            acc1[t] = __builtin_amdgcn_mfma_f32_16x16x32_bf16(af1, bfr, acc1[t], 0, 0, 0);
        }
        __syncthreads();
    }

    // ---- epilogue: relu(HH+l1b) @ l2W, sigmoid, write fp32 out ----
    float bb[8];
#pragma unroll
    for (int t = 0; t < 8; ++t) bb[t] = l1b[t * 16 + m];
    float b20 = l2b[0], b21 = l2b[1];
#pragma unroll
    for (int half = 0; half < 2; ++half) {
#pragma unroll
        for (int r = 0; r < 4; ++r) {
            float p0 = 0.f, p1 = 0.f;
#pragma unroll
            for (int t = 0; t < 8; ++t) {
                int col = t * 16 + m;
                f32x4 a = half ? acc1[t] : acc0[t];
                float v = fmaxf(a[r] + bb[t], 0.f);
                p0 = fmaf(v, w2s[col * 2 + 0], p0);
                p1 = fmaf(v, w2s[col * 2 + 1], p1);
            }
#pragma unroll
            for (int mask = 1; mask < 16; mask <<= 1) {
                p0 += __shfl_xor(p0, mask);
                p1 += __shfl_xor(p1, mask);
            }
            if (m == 0) {
                int row = bm + wave * 32 + half * 16 + quad * 4 + r;
                if (row < nrows) {
                    out[(size_t)row * 2 + 0] = 1.f / (1.f + __expf(-(p0 + b20)));
                    out[(size_t)row * 2 + 1] = 1.f / (1.f + __expf(-(p1 + b21)));
                }
            }
        }
    }
}

// ---------------------------------------------------------------- CSR build
__global__ __launch_bounds__(256)
void hist_kernel(const int* __restrict__ dst, int* __restrict__ deg)
{
    int e = blockIdx.x * 256 + threadIdx.x;
    if (e < NE) atomicAdd(&deg[dst[e]], 1);
}

__global__ __launch_bounds__(1024)
void scan1_kernel(const int* __restrict__ deg, int* __restrict__ off,
                  int* __restrict__ bsum)
{
    __shared__ int buf[1024];
    int tx = threadIdx.x;
    int i = blockIdx.x * 1024 + tx;
    int v = (i < NN) ? deg[i] : 0;
    buf[tx] = v;
    __syncthreads();
    for (int s = 1; s < 1024; s <<= 1) {
        int t = (tx >= s) ? buf[tx - s] : 0;
        __syncthreads();
        buf[tx] += t;
        __syncthreads();
    }
    if (i < NN) off[i] = buf[tx] - v;
    if (tx == 1023) bsum[blockIdx.x] = buf[1023];
}

__global__ __launch_bounds__(64)
void scan2_kernel(int* __restrict__ bsum)
{
    __shared__ int buf[64];
    int tx = threadIdx.x;
    int v = (tx < SCAN_BLOCKS) ? bsum[tx] : 0;
    buf[tx] = v;
    __syncthreads();
    for (int s = 1; s < 64; s <<= 1) {
        int t = (tx >= s) ? buf[tx - s] : 0;
        __syncthreads();
        buf[tx] += t;
        __syncthreads();
    }
    if (tx < SCAN_BLOCKS) bsum[tx] = buf[tx] - v;
}

__global__ __launch_bounds__(1024)
void scan3_kernel(int* __restrict__ off, const int* __restrict__ bsum)
{
    int i = blockIdx.x * 1024 + threadIdx.x;
    if (i < NN) off[i] += bsum[blockIdx.x];
    if (i == 0) off[NN] = NE;
}

__global__ __launch_bounds__(256)
void permute_kernel(const int* __restrict__ src, const int* __restrict__ dst,
                    const float* __restrict__ w, const int* __restrict__ off,
                    int* __restrict__ cursor, unsigned long long* __restrict__ esw)
{
    int e = blockIdx.x * 256 + threadIdx.x;
    if (e >= NE) return;
    int d = dst[e];
    int p = off[d] + atomicAdd(&cursor[d], 1);
    unsigned long long packed = (unsigned int)src[e] |
        ((unsigned long long)(unsigned int)__float_as_uint(w[e]) << 32);
    __builtin_nontemporal_store(packed, &esw[p]);
}

// ---------------------------------------------------------------- gather agg (wave/node)
// One wave per node; one coalesced dword load per edge (lane i -> ch 2i,2i+1).
// Deep pipeline: edges processed in groups of 8 (8 loads issued back-to-back,
// dual accumulators). Lanes past e1 stage pk=0 -> w=+0, src=0: contributes
// exactly 0, so edge count rounds up to 8 with NO tail code (keeps the VMEM
// queue full; R6's unroll-4 drained vmcnt->0 every 4 edges = latency-bound).
__global__ __launch_bounds__(256)
void gather_agg(const ushort* __restrict__ hw,
                const unsigned long long* __restrict__ esw,
                const int* __restrict__ off, const float* __restrict__ gbias,
                ushort* __restrict__ agg)
{
    const int wid  = blockIdx.x * 4 + (threadIdx.x >> 6);   // node id
    const int lane = threadIdx.x & 63;
    if (wid >= NN) return;
    const int e0 = off[wid], e1 = off[wid + 1];
    float a0 = 0.f, a1 = 0.f, b0 = 0.f, b1 = 0.f;
    const ushort* hp = hw + lane * 2;
    for (int base = e0; base < e1; base += 64) {
        int idx = base + lane;
        unsigned long long pk = (idx < e1) ? esw[idx] : 0ULL;
        int slo = (int)(unsigned int)(pk & 0xffffffffULL);
        int shi = (int)(unsigned int)(pk >> 32);
        int cnt = e1 - base; if (cnt > 64) cnt = 64;
        int cnt8 = (cnt + 7) & ~7;                 // round up: extras are +0.0*row0
        for (int j = 0; j < cnt8; j += 8) {
            int   ss[8];
            float ww[8];
            unsigned int rv[8];
#pragma unroll
            for (int k = 0; k < 8; ++k) {
                ss[k] = __builtin_amdgcn_readlane(slo, j + k);
                ww[k] = __int_as_float(__builtin_amdgcn_readlane(shi, j + k));
            }
#pragma unroll
            for (int k = 0; k < 8; ++k)
                rv[k] = *(const unsigned int*)(hp + (size_t)ss[k] * 128);
#pragma unroll
            for (int k = 0; k < 8; k += 2) {
                a0 = fmaf(bf2f((ushort)(rv[k]   & 0xffff)), ww[k],   a0);
                a1 = fmaf(bf2f((ushort)(rv[k]   >> 16)),    ww[k],   a1);
                b0 = fmaf(bf2f((ushort)(rv[k+1] & 0xffff)), ww[k+1], b0);
                b1 = fmaf(bf2f((ushort)(rv[k+1] >> 16)),    ww[k+1], b1);
            }
        }
    }
    a0 += b0; a1 += b1;
    float g0 = gbias[lane * 2], g1 = gbias[lane * 2 + 1];
    unsigned int o = (unsigned int)f2bf(fmaxf(a0 + g0, 0.f)) |
                     ((unsigned int)f2bf(fmaxf(a1 + g1, 0.f)) << 16);
    *(unsigned int*)(agg + (size_t)wid * 128 + lane * 2) = o;
}

// ---------------------------------------------------------------- launch
extern "C" void kernel_launch(void* const* d_in, const int* in_sizes, int n_in,
                              void* d_out, int out_size, void* d_ws, size_t ws_size,
                              hipStream_t stream)
{
    const float* x    = (const float*)d_in[0];
    const int*   esrc = (const int*)  d_in[1];
    const int*   edst = (const int*)  d_in[2];
    const float* ew   = (const float*)d_in[3];
    const float* preW = (const float*)d_in[4];
    const float* preb = (const float*)d_in[5];
    const float* f1W  = (const float*)d_in[6];
    const float* f1b  = (const float*)d_in[7];
    const float* f2W  = (const float*)d_in[8];
    const float* f2b  = (const float*)d_in[9];
    const float* gW   = (const float*)d_in[10];
    const float* gb   = (const float*)d_in[11];
    const float* fgW  = (const float*)d_in[12];
    const float* fgb  = (const float*)d_in[13];
    const float* l1W  = (const float*)d_in[14];
    const float* l1b  = (const float*)d_in[15];
    const float* l2W  = (const float*)d_in[16];
    const float* l2b  = (const float*)d_in[17];
    float* out = (float*)d_out;

    ushort* wt   = (ushort*)d_ws;
    ushort* wf1  = wt;                          //   4096
    ushort* wf2  = wf1 + 4096;                  //   4096
    ushort* wg   = wf2 + 4096;                  //  98304
    ushort* wfg  = wg  + 98304;                 // 196608
    ushort* wl1  = wfg + 196608;                //  32768
    ushort* h0b  = wl1 + 32768;                 // N*32
    ushort* nidb = h0b  + (size_t)NN * 32;      // N*128
    ushort* hwb  = nidb + (size_t)NN * 128;     // N*128 row-major
    ushort* aggb = hwb  + (size_t)NN * 128;     // N*128 row-major
    ushort* endu = aggb + (size_t)NN * 128;
    unsigned long long* esw = (unsigned long long*)(((uintptr_t)endu + 15) & ~(uintptr_t)15);
    int*   deg   = (int*)(esw + NE);
    int*   off   = deg + NN;
    int*   cursor= off + NN + 1;
    int*   bsum  = cursor + NN;                 // 64

    const int gblocks = (NN + 63) / 64;         // 782
    const int eblocks = (NE + 255) / 256;
    const int wblocks = (NN + 3) / 4;           // 12500 (4 waves/block)

    convert_weights<<<(335872 + 255) / 256, 256, 0, stream>>>(f1W, f2W, gW, fgW, l1W, wt);

    // ---- CSR build (reused by all 6 layers) ----
    hipMemsetAsync(deg, 0, (size_t)NN * sizeof(int), stream);
    hipMemsetAsync(cursor, 0, (size_t)NN * sizeof(int), stream);
    hist_kernel<<<eblocks, 256, 0, stream>>>(edst, deg);
    scan1_kernel<<<SCAN_BLOCKS, 1024, 0, stream>>>(deg, off, bsum);
    scan2_kernel<<<1, 64, 0, stream>>>(bsum);
    scan3_kernel<<<SCAN_BLOCKS, 1024, 0, stream>>>(off, bsum);
    permute_kernel<<<eblocks, 256, 0, stream>>>(esrc, edst, ew, off, cursor, esw);

    // ---- network ----
    preproc_kernel<<<(NN + 255) / 256, 256, 0, stream>>>(x, preW, preb, h0b);
    gemm_mfma<<<gblocks, 128, 0, stream>>>(h0b, 32, wf1, f1b, nidb, NN);
    // fc_in2 + gcn0 : hwb = relu(h0@Wf2+b) @ Wg0
    gemm_fused<<<gblocks, 128, 0, stream>>>(h0b, 32, nullptr, 0, wf2, f2b,
                                            wg, hwb, NN);
    for (int l = 0; l < 6; ++l) {
        gather_agg<<<wblocks, 256, 0, stream>>>(hwb, esw, off,
                                                gb + (size_t)l * 128, aggb);
        if (l < 5) {
            gemm_fused<<<gblocks, 128, 0, stream>>>(nidb, 128, aggb, 128,
                                                    wfg + (size_t)l * 32768,
                                                    fgb + (size_t)l * 128,
                                                    wg + (size_t)(l + 1) * 16384,
                                                    hwb, NN);
        }
    }
    gemm_last<<<gblocks, 128, 0, stream>>>(nidb, aggb,
                                           wfg + (size_t)5 * 32768,
                                           fgb + (size_t)5 * 128,
                                           wl1, l1b, l2W, l2b, out, NN);
}